// Round 14
// baseline (31.356 us; speedup 1.0000x reference)
//
#include <hip/hip_runtime.h>

#define HW 128
#define PLANE (HW * HW)              // 16384
#define SCALE 0.17677669529663687f   // 32^-0.5
#define FENCE() asm volatile("" ::: "memory")

// 2 output rows per thread: k/v rows yb-1..yb+2 loaded ONCE serve both rows
// (2 row-loads per output row vs 3 -> 1.4x fewer logical request bytes; R12
// analysis shows we're bound on aggregate request BW, not HBM/VALU/latency).
// Thread = 4px x 2 rows x 16ch; lane = (strip<<1)|h2; wave = 32 strips x h2
// pair = 2 rows; block = 4 waves = 8 rows (same tile/halo as R12).
// 16 QK steps + 16 PV steps (step = one channel: 4 k/v rows + 2 q rows),
// A/B windows, 1-2 step load lookahead, fence-pinned. R13 BUG FIXED: QK
// schedule was missing steps 14,15 (4 of 32 channels absent from logits).
// Logit reduce via lane-pair shfl_xor(1). Stores in two 64B-complete phases.
// Grid = 4b*4h*16ytiles = 256 blocks x 256 thr = 1024 waves (1/SIMD).
__global__ __launch_bounds__(256, 1) void natt3x3_kernel(
    const float* __restrict__ q,
    const float* __restrict__ k,
    const float* __restrict__ v,
    float* __restrict__ out) {
  const int tid  = threadIdx.x;
  const int lane = tid & 63;
  const int w    = tid >> 6;            // wave = row-pair in tile (0..3)
  const int h2   = lane & 1;            // channel sub-quad selector
  const int s    = lane >> 1;           // strip 0..31
  const int x0   = s << 2;
  const int bid  = blockIdx.x;          // ((b*4+head)*16 + ytile)
  const int ytile = bid & 15;
  const int head  = (bid >> 4) & 3;
  const int b     = bid >> 6;
  const int yb    = (ytile << 3) | (w << 1);   // first of my 2 output rows

  const size_t cbase = (size_t)(b * 128 + head * 32 + h2 * 4) * PLANE;
  const float* kp0 = k + cbase;
  const float* vp0 = v + cbase;
  const float* qp0 = q + cbase;

  // 4 loaded k/v rows: yb-1 .. yb+2 (clamped; OOB fixed by softmax mask)
  int yr[4];
#pragma unroll
  for (int r = 0; r < 4; ++r) {
    int yy = yb - 1 + r; yy = yy < 0 ? 0 : (yy > HW - 1 ? HW - 1 : yy);
    yr[r] = yy * HW + x0;
  }
  const int yq0 = yb * HW + x0, yq1 = (yb + 1) * HW + x0;

  float l[2][4][9];
#pragma unroll
  for (int t = 0; t < 2; ++t)
#pragma unroll
    for (int i = 0; i < 4; ++i)
#pragma unroll
      for (int j = 0; j < 9; ++j) l[t][i][j] = 0.f;

  float4 kA[4], qA[2], kB[4], qB[2];   // QK windows
  float4 vA[4], vB[4];                  // PV windows
  float a0[4][8], a1[4][8];             // per-phase channel outputs (assign-only)

  // step S = channel: ch = (S>>2)*8 + (S&3)  (h2*4 folded into cbase)
#define LDQK(KW, QW, S) do {                                                  \
    const float* kp = kp0 + (size_t)(((S) >> 2) * 8 + ((S) & 3)) * PLANE;     \
    const float* qp = qp0 + (size_t)(((S) >> 2) * 8 + ((S) & 3)) * PLANE;     \
    KW[0] = *reinterpret_cast<const float4*>(kp + yr[0]);                     \
    KW[1] = *reinterpret_cast<const float4*>(kp + yr[1]);                     \
    KW[2] = *reinterpret_cast<const float4*>(kp + yr[2]);                     \
    KW[3] = *reinterpret_cast<const float4*>(kp + yr[3]);                     \
    QW[0] = *reinterpret_cast<const float4*>(qp + yq0);                       \
    QW[1] = *reinterpret_cast<const float4*>(qp + yq1);                       \
  } while (0)

#define LDPV(VW, S) do {                                                      \
    const float* vp = vp0 + (size_t)(((S) >> 2) * 8 + ((S) & 3)) * PLANE;     \
    VW[0] = *reinterpret_cast<const float4*>(vp + yr[0]);                     \
    VW[1] = *reinterpret_cast<const float4*>(vp + yr[1]);                     \
    VW[2] = *reinterpret_cast<const float4*>(vp + yr[2]);                     \
    VW[3] = *reinterpret_cast<const float4*>(vp + yr[3]);                     \
  } while (0)

  // loaded row r feeds: t=0 with dy=r (r<=2), t=1 with dy=r-1 (r>=1)
#define CMPQK(KW, QW) do {                                                    \
    const float qs0[4] = {QW[0].x * SCALE, QW[0].y * SCALE,                   \
                          QW[0].z * SCALE, QW[0].w * SCALE};                  \
    const float qs1[4] = {QW[1].x * SCALE, QW[1].y * SCALE,                   \
                          QW[1].z * SCALE, QW[1].w * SCALE};                  \
    _Pragma("unroll")                                                         \
    for (int r = 0; r < 4; ++r) {                                             \
      float4 kq = KW[r];                                                      \
      float n0 = __shfl_up(kq.w, 2), n5 = __shfl_down(kq.x, 2);               \
      const float n[6] = {n0, kq.x, kq.y, kq.z, kq.w, n5};                    \
      if (r <= 2) {                                                           \
        _Pragma("unroll")                                                     \
        for (int i = 0; i < 4; ++i)                                           \
          _Pragma("unroll")                                                   \
          for (int jj = 0; jj < 3; ++jj)                                      \
            l[0][i][r * 3 + jj] += qs0[i] * n[i + jj];                        \
      }                                                                       \
      if (r >= 1) {                                                           \
        _Pragma("unroll")                                                     \
        for (int i = 0; i < 4; ++i)                                           \
          _Pragma("unroll")                                                   \
          for (int jj = 0; jj < 3; ++jj)                                      \
            l[1][i][(r - 1) * 3 + jj] += qs1[i] * n[i + jj];                  \
      }                                                                       \
    }                                                                         \
  } while (0)

  // one channel's PV: 9-weight dot per (t,i); assign into a0/a1[ci]
#define CMPPV(VW, S) do {                                                     \
    const int ci = ((((S) >> 2) & 1) * 4) + ((S) & 3);                        \
    float c0[4] = {0.f, 0.f, 0.f, 0.f}, c1[4] = {0.f, 0.f, 0.f, 0.f};         \
    _Pragma("unroll")                                                         \
    for (int r = 0; r < 4; ++r) {                                             \
      float4 vq = VW[r];                                                      \
      float n0 = __shfl_up(vq.w, 2), n5 = __shfl_down(vq.x, 2);               \
      const float n[6] = {n0, vq.x, vq.y, vq.z, vq.w, n5};                    \
      if (r <= 2) {                                                           \
        _Pragma("unroll")                                                     \
        for (int i = 0; i < 4; ++i)                                           \
          _Pragma("unroll")                                                   \
          for (int jj = 0; jj < 3; ++jj)                                      \
            c0[i] += l[0][i][r * 3 + jj] * n[i + jj];                         \
      }                                                                       \
      if (r >= 1) {                                                           \
        _Pragma("unroll")                                                     \
        for (int i = 0; i < 4; ++i)                                           \
          _Pragma("unroll")                                                   \
          for (int jj = 0; jj < 3; ++jj)                                      \
            c1[i] += l[1][i][(r - 1) * 3 + jj] * n[i + jj];                   \
      }                                                                       \
    }                                                                         \
    _Pragma("unroll")                                                         \
    for (int i = 0; i < 4; ++i) { a0[i][ci] = c0[i]; a1[i][ci] = c1[i]; }     \
  } while (0)

#define ST1(AT, T, P) do {                                                    \
    _Pragma("unroll")                                                         \
    for (int i = 0; i < 4; ++i) {                                             \
      float* op = out + ((size_t)(b * PLANE + (yb + (T)) * HW + x0 + i)) * 128\
                  + head * 32 + h2 * 4 + (P) * 16;                            \
      float4 o;                                                               \
      o.x = fmaxf(AT[i][0], 0.f); o.y = fmaxf(AT[i][1], 0.f);                 \
      o.z = fmaxf(AT[i][2], 0.f); o.w = fmaxf(AT[i][3], 0.f);                 \
      *reinterpret_cast<float4*>(op) = o;                                     \
      o.x = fmaxf(AT[i][4], 0.f); o.y = fmaxf(AT[i][5], 0.f);                 \
      o.z = fmaxf(AT[i][6], 0.f); o.w = fmaxf(AT[i][7], 0.f);                 \
      *reinterpret_cast<float4*>(op + 8) = o;                                 \
    }                                                                         \
  } while (0)

  // ---- QK: 16 steps, pattern CMP(s); LD(s+2) keeps 1-2 windows in flight --
  LDQK(kA, qA, 0); FENCE();
  LDQK(kB, qB, 1); FENCE();
  CMPQK(kA, qA); LDQK(kA, qA, 2);  FENCE();
  CMPQK(kB, qB); LDQK(kB, qB, 3);  FENCE();
  CMPQK(kA, qA); LDQK(kA, qA, 4);  FENCE();
  CMPQK(kB, qB); LDQK(kB, qB, 5);  FENCE();
  CMPQK(kA, qA); LDQK(kA, qA, 6);  FENCE();
  CMPQK(kB, qB); LDQK(kB, qB, 7);  FENCE();
  CMPQK(kA, qA); LDQK(kA, qA, 8);  FENCE();
  CMPQK(kB, qB); LDQK(kB, qB, 9);  FENCE();
  CMPQK(kA, qA); LDQK(kA, qA, 10); FENCE();
  CMPQK(kB, qB); LDQK(kB, qB, 11); FENCE();
  CMPQK(kA, qA); LDQK(kA, qA, 12); FENCE();
  CMPQK(kB, qB); LDQK(kB, qB, 13); FENCE();
  CMPQK(kA, qA); LDQK(kA, qA, 14); FENCE();   // R13 missing step
  CMPQK(kB, qB); LDQK(kB, qB, 15); FENCE();   // R13 missing step
  CMPQK(kA, qA); LDPV(vA, 0);      FENCE();   // PV prefetch replaces LD(16)
  CMPQK(kB, qB); LDPV(vB, 1);      FENCE();

  // ---- lane-pair reduce: 16 ch + partner's 16 = full 32 ----
#pragma unroll
  for (int t = 0; t < 2; ++t)
#pragma unroll
    for (int i = 0; i < 4; ++i)
#pragma unroll
      for (int j = 0; j < 9; ++j) l[t][i][j] += __shfl_xor(l[t][i][j], 1);

  // ---- mask + softmax per (row, pixel); PV steps 0,1 in flight ----
#pragma unroll
  for (int t = 0; t < 2; ++t)
#pragma unroll
  for (int i = 0; i < 4; ++i) {
    const int yy = yb + t, xp = x0 + i;
    float mk[9];
#pragma unroll
    for (int dy = 0; dy < 3; ++dy)
#pragma unroll
      for (int dx = 0; dx < 3; ++dx) {
        bool ok = ((unsigned)(yy + dy - 1) < (unsigned)HW) &&
                  ((unsigned)(xp + dx - 1) < (unsigned)HW);
        mk[dy * 3 + dx] = ok ? 1.f : 0.f;
      }
    float m = -1e30f;
#pragma unroll
    for (int j = 0; j < 9; ++j) {
      float tt = l[t][i][j] * mk[j];
      l[t][i][j] = tt;
      m = fmaxf(m, tt);
    }
    float sum = 0.f;
#pragma unroll
    for (int j = 0; j < 9; ++j) {
      float e = __expf(l[t][i][j] - m);
      l[t][i][j] = e;
      sum += e;
    }
    float inv = 1.f / sum;
#pragma unroll
    for (int j = 0; j < 9; ++j) l[t][i][j] *= inv * mk[j];
  }
  FENCE();

  // ---- PV: 16 steps; stores after steps 0-7 (phase 0) and 8-15 (phase 1) --
  CMPPV(vA, 0);  LDPV(vA, 2);  FENCE();
  CMPPV(vB, 1);  LDPV(vB, 3);  FENCE();
  CMPPV(vA, 2);  LDPV(vA, 4);  FENCE();
  CMPPV(vB, 3);  LDPV(vB, 5);  FENCE();
  CMPPV(vA, 4);  LDPV(vA, 6);  FENCE();
  CMPPV(vB, 5);  LDPV(vB, 7);  FENCE();
  CMPPV(vA, 6);  LDPV(vA, 8);  FENCE();
  CMPPV(vB, 7);  LDPV(vB, 9);  FENCE();
  ST1(a0, 0, 0); ST1(a1, 1, 0); FENCE();     // phase-0 stores: ch 0..15
  CMPPV(vA, 8);  LDPV(vA, 10); FENCE();
  CMPPV(vB, 9);  LDPV(vB, 11); FENCE();
  CMPPV(vA, 10); LDPV(vA, 12); FENCE();
  CMPPV(vB, 11); LDPV(vB, 13); FENCE();
  CMPPV(vA, 12); LDPV(vA, 14); FENCE();
  CMPPV(vB, 13); LDPV(vB, 15); FENCE();
  CMPPV(vA, 14); FENCE();
  CMPPV(vB, 15); FENCE();
  ST1(a0, 0, 1); ST1(a1, 1, 1);              // phase-1 stores: ch 16..31

#undef LDQK
#undef LDPV
#undef CMPQK
#undef CMPPV
#undef ST1
}

extern "C" void kernel_launch(void* const* d_in, const int* in_sizes, int n_in,
                              void* d_out, int out_size, void* d_ws, size_t ws_size,
                              hipStream_t stream) {
  const float* q = (const float*)d_in[0];
  const float* k = (const float*)d_in[1];
  const float* v = (const float*)d_in[2];
  float* out = (float*)d_out;
  // grid: B(4) * heads(4) * ytiles(16) = 256 blocks, 256 threads (4 waves)
  natt3x3_kernel<<<256, 256, 0, stream>>>(q, k, v, out);
}

// Round 15
// 27.597 us; speedup vs baseline: 1.1362x; 1.1362x over previous
//
#include <hip/hip_runtime.h>

#define HW 128
#define PLANE (HW * HW)              // 16384
#define SCALE 0.17677669529663687f   // 32^-0.5
#define FENCE() asm volatile("" ::: "memory")

// R12 (best: 29.5us) + XCD-aware blockIdx swizzle (T1). Grid = 256 blocks,
// 8 XCDs, HW round-robins bid%8 -> without swizzle each XCD touches all 16
// (b,head) images (8x duplicated L2 fills, cross-XCD halo refetch). Swizzle
// maps bid so XCD x gets exactly images {2x,2x+1}, all 16 ytiles co-resident
// (32 blocks/XCD at 1 block/CU): k/v 3x-reuse + tile halos confined to one L2.
// Everything else identical to R12: thread = 4px x 16ch, lane=(strip<<1)|h2,
// wave = one row, block = 8 waves = 8 rows; fence-pinned 3-buffer pipeline;
// lane-pair logit reduce; fused normal-store phase (64B-sector-complete).
__global__ __launch_bounds__(512, 2) void natt3x3_kernel(
    const float* __restrict__ q,
    const float* __restrict__ k,
    const float* __restrict__ v,
    float* __restrict__ out) {
  const int tid  = threadIdx.x;
  const int lane = tid & 63;
  const int w    = tid >> 6;            // wave index in block = row in tile (0..7)
  const int h2   = lane & 1;            // channel sub-quad selector
  const int s    = lane >> 1;           // strip 0..31
  const int x0   = s << 2;              // first pixel x of strip
  const int bid  = blockIdx.x;
  // XCD swizzle: xcd = bid&7 (HW round-robin); img = (xcd<<1)|((bid>>3)&1)
  const int img   = ((bid & 7) << 1) | ((bid >> 3) & 1);   // b*4+head, 0..15
  const int ytile = bid >> 4;                              // 0..15
  const int head  = img & 3;
  const int b     = img >> 2;
  const int y     = (ytile << 3) | w;

  const size_t cbase = (size_t)(b * 128 + head * 32 + h2 * 4) * PLANE;
  const int yx = y * HW + x0;

  int yrow[3];
#pragma unroll
  for (int dy = 0; dy < 3; ++dy) {
    int yy = y + dy - 1; yy = yy < 0 ? 0 : (yy > HW - 1 ? HW - 1 : yy);
    yrow[dy] = yy * HW;
  }

  float l[4][9];
#pragma unroll
  for (int i = 0; i < 4; ++i)
#pragma unroll
    for (int j = 0; j < 9; ++j) l[i][j] = 0.f;

  float acc[4][16];     // all 16 channels per pixel, stored once at the end
#pragma unroll
  for (int i = 0; i < 4; ++i)
#pragma unroll
    for (int c = 0; c < 16; ++c) acc[i][c] = 0.f;

  float4 qv4[3][4];      // q quads per buffer
  float4 rv[3][3][4];    // k/v rows [buf][dy][c]

#define LQK(B, G) do {                                                       \
    const size_t cb = cbase + (size_t)((G) * 8) * PLANE;                     \
    const float* qg = q + cb + yx;                                           \
    const float* kg = k + cb;                                                \
    _Pragma("unroll")                                                        \
    for (int c = 0; c < 4; ++c)                                              \
      qv4[B][c] = *reinterpret_cast<const float4*>(qg + (size_t)c * PLANE);  \
    _Pragma("unroll")                                                        \
    for (int c = 0; c < 4; ++c)                                              \
      _Pragma("unroll")                                                      \
      for (int dy = 0; dy < 3; ++dy)                                         \
        rv[B][dy][c] = *reinterpret_cast<const float4*>(                     \
            kg + (size_t)c * PLANE + yrow[dy] + x0);                         \
  } while (0)

#define LPV(B, G) do {                                                       \
    const float* vg = v + cbase + (size_t)((G) * 8) * PLANE;                 \
    _Pragma("unroll")                                                        \
    for (int c = 0; c < 4; ++c)                                              \
      _Pragma("unroll")                                                      \
      for (int dy = 0; dy < 3; ++dy)                                         \
        rv[B][dy][c] = *reinterpret_cast<const float4*>(                     \
            vg + (size_t)c * PLANE + yrow[dy] + x0);                         \
  } while (0)

#define CQK(B) do {                                                          \
    _Pragma("unroll")                                                        \
    for (int c = 0; c < 4; ++c) {                                            \
      const float qa[4] = {qv4[B][c].x * SCALE, qv4[B][c].y * SCALE,         \
                           qv4[B][c].z * SCALE, qv4[B][c].w * SCALE};        \
      _Pragma("unroll")                                                      \
      for (int dy = 0; dy < 3; ++dy) {                                       \
        float4 kq = rv[B][dy][c];                                            \
        float n0 = __shfl_up(kq.w, 2);                                       \
        float n5 = __shfl_down(kq.x, 2);                                     \
        const float n[6] = {n0, kq.x, kq.y, kq.z, kq.w, n5};                 \
        _Pragma("unroll")                                                    \
        for (int i = 0; i < 4; ++i)                                          \
          _Pragma("unroll")                                                  \
          for (int j = 0; j < 3; ++j)                                        \
            l[i][dy * 3 + j] += qa[i] * n[i + j];                            \
      }                                                                      \
    }                                                                        \
  } while (0)

#define CPV(B, G) do {                                                       \
    _Pragma("unroll")                                                        \
    for (int c = 0; c < 4; ++c)                                              \
      _Pragma("unroll")                                                      \
      for (int dy = 0; dy < 3; ++dy) {                                       \
        float4 vq = rv[B][dy][c];                                            \
        float n0 = __shfl_up(vq.w, 2);                                       \
        float n5 = __shfl_down(vq.x, 2);                                     \
        const float n[6] = {n0, vq.x, vq.y, vq.z, vq.w, n5};                 \
        _Pragma("unroll")                                                    \
        for (int i = 0; i < 4; ++i)                                          \
          _Pragma("unroll")                                                  \
          for (int j = 0; j < 3; ++j)                                        \
            acc[i][(G) * 4 + c] += l[i][dy * 3 + j] * n[i + j];              \
      }                                                                      \
  } while (0)

  // ---- QK: fence-pinned schedule, 2-3 load-groups in flight ----
  LQK(0, 0); FENCE();
  LQK(1, 1); FENCE();
  LQK(2, 2); FENCE();
  CQK(0);    FENCE();
  LQK(0, 3); FENCE();
  CQK(1);    FENCE();
  LPV(1, 0); FENCE();
  CQK(2);    FENCE();
  LPV(2, 1); FENCE();
  CQK(0);    FENCE();   // group 3
  LPV(0, 2); FENCE();

  // ---- lane-pair reduce: my 16 channels + partner's 16 = full 32 ----
#pragma unroll
  for (int i = 0; i < 4; ++i)
#pragma unroll
    for (int j = 0; j < 9; ++j) l[i][j] += __shfl_xor(l[i][j], 1);

  // ---- mask + softmax per pixel (3 PV load-groups in flight under this) ----
#pragma unroll
  for (int i = 0; i < 4; ++i) {
    const int xp = x0 + i;
    float mk[9];
#pragma unroll
    for (int dy = 0; dy < 3; ++dy)
#pragma unroll
      for (int dx = 0; dx < 3; ++dx) {
        bool ok = ((unsigned)(y + dy - 1) < (unsigned)HW) &&
                  ((unsigned)(xp + dx - 1) < (unsigned)HW);
        mk[dy * 3 + dx] = ok ? 1.f : 0.f;
      }
    float m = -1e30f;
#pragma unroll
    for (int j = 0; j < 9; ++j) {
      float t = l[i][j] * mk[j];
      l[i][j] = t;
      m = fmaxf(m, t);
    }
    float sum = 0.f;
#pragma unroll
    for (int j = 0; j < 9; ++j) {
      float e = __expf(l[i][j] - m);
      l[i][j] = e;
      sum += e;
    }
    float inv = 1.f / sum;
#pragma unroll
    for (int j = 0; j < 9; ++j) l[i][j] *= inv * mk[j];
  }
  FENCE();

  // ---- PV: accumulate only (no stores yet) ----
  CPV(1, 0); FENCE();
  LPV(1, 3); FENCE();
  CPV(2, 1); FENCE();
  CPV(0, 2); FENCE();
  CPV(1, 3);

  // ---- single store phase: 16 normal float4, back-to-back ----
  const size_t obase = ((size_t)(b * PLANE + y * HW)) * 128 + head * 32 + h2 * 4;
#pragma unroll
  for (int i = 0; i < 4; ++i) {
    float* op = out + obase + (size_t)(x0 + i) * 128;
#pragma unroll
    for (int g = 0; g < 4; ++g) {
      float4 o;
      o.x = fmaxf(acc[i][g * 4 + 0], 0.f);
      o.y = fmaxf(acc[i][g * 4 + 1], 0.f);
      o.z = fmaxf(acc[i][g * 4 + 2], 0.f);
      o.w = fmaxf(acc[i][g * 4 + 3], 0.f);
      *reinterpret_cast<float4*>(op + g * 8) = o;
    }
  }

#undef LQK
#undef LPV
#undef CQK
#undef CPV
}

extern "C" void kernel_launch(void* const* d_in, const int* in_sizes, int n_in,
                              void* d_out, int out_size, void* d_ws, size_t ws_size,
                              hipStream_t stream) {
  const float* q = (const float*)d_in[0];
  const float* k = (const float*)d_in[1];
  const float* v = (const float*)d_in[2];
  float* out = (float*)d_out;
  // grid: 256 blocks (XCD-swizzled decode in-kernel), 512 threads (8 waves)
  natt3x3_kernel<<<256, 512, 0, stream>>>(q, k, v, out);
}